// Round 4
// baseline (793.276 us; speedup 1.0000x reference)
//
#include <hip/hip_runtime.h>

// EideticLinearLayer via bf16 split-precision MFMA.
// out = X @ W^T + bias ; idx = searchsorted_left(quantiles[col], wx)
// X: [16384,256] f32, W: [4096,256] f32, bias: [4096], quantiles: [4096,31]
//
// fp32 -> (hi, mid) bf16 split; wx approx = hi*hi' + hi*mid' + mid*hi' via
// v_mfma_f32_16x16x32_bf16. Boundary-ambiguous values recomputed with an
// exact fp32 fmaf chain (reference order) -> indices bitwise-exact.
//
// R4: VGPR (88) caps us at 16 waves/CU, so attack per-wave stall instead:
// 3-deep staging pipeline, raw s_barrier + counted vmcnt(3) (never drain to
// 0 in-loop). Tile 128x64 (24KB/step x3 = 72KB LDS, still 2 blocks/CU).
// Wave grid 4x2: each wave owns 32 contiguous cols -> full-128B-line stores
// preserved (R2 fix). Per-accumulator MFMA order unchanged -> bit-identical.

#define B_DIM 16384
#define K_DIM 256
#define N_DIM 4096
#define NQ 31
#define QCAP 2048
#define DELTA 1e-3f
#define STEP_BYTES 24576

typedef __bf16 bf16x8 __attribute__((ext_vector_type(8)));
typedef float f32x4 __attribute__((ext_vector_type(4)));
typedef unsigned short ushort8 __attribute__((ext_vector_type(8)));

typedef const __attribute__((address_space(1))) unsigned int gu32;
typedef __attribute__((address_space(3))) unsigned int lu32;

// ---------------------------------------------------------------------------
// split_pack: one (128-row tile, ks) unit per block -> plane image
// [tile][ks][kb(4)][row(128)][8 k] per plane. Coalesced reads and writes.
// ---------------------------------------------------------------------------
__global__ __launch_bounds__(256)
void split_pack(const float* __restrict__ X, const float* __restrict__ W,
                unsigned short* __restrict__ Xhi, unsigned short* __restrict__ Xmid,
                unsigned short* __restrict__ Whi, unsigned short* __restrict__ Wmid)
{
    const int b = blockIdx.x;
    const int tid = threadIdx.x;
    const int r = tid >> 1, ch = tid & 1;

    const float* src;
    unsigned short *dhi, *dmid;
    if (b < 1024) {                      // X: 128 tiles x 8 ks
        const unsigned u = b;
        src = X + ((size_t)(u >> 3) * 128 + r) * K_DIM + (u & 7) * 32 + ch * 16;
        dhi = Xhi + (size_t)u * 4096; dmid = Xmid + (size_t)u * 4096;
    } else {                             // W: 32 tiles x 8 ks
        const unsigned u = b - 1024;
        src = W + ((size_t)(u >> 3) * 128 + r) * K_DIM + (u & 7) * 32 + ch * 16;
        dhi = Whi + (size_t)u * 4096; dmid = Wmid + (size_t)u * 4096;
    }

    float4 v0 = *(const float4*)src;
    float4 v1 = *(const float4*)(src + 4);
    float4 v2 = *(const float4*)(src + 8);
    float4 v3 = *(const float4*)(src + 12);
    float xs[16] = {v0.x, v0.y, v0.z, v0.w, v1.x, v1.y, v1.z, v1.w,
                    v2.x, v2.y, v2.z, v2.w, v3.x, v3.y, v3.z, v3.w};
    ushort8 h[2], m[2];
#pragma unroll
    for (int j = 0; j < 16; ++j) {
        float x = xs[j];
        __bf16 hb = (__bf16)x;           // RNE
        float hf = (float)hb;
        __bf16 mb = (__bf16)(x - hf);    // residual, RNE
        h[j >> 3][j & 7] = __builtin_bit_cast(unsigned short, hb);
        m[j >> 3][j & 7] = __builtin_bit_cast(unsigned short, mb);
    }
    const unsigned off = (unsigned)(ch * 2) * 1024u + (unsigned)r * 8u;
    *(ushort8*)(dhi + off)         = h[0];
    *(ushort8*)(dhi + off + 1024)  = h[1];
    *(ushort8*)(dmid + off)        = m[0];
    *(ushort8*)(dmid + off + 1024) = m[1];
}

// ---------------------------------------------------------------------------
// Main fused kernel: 128x64 tile, 8 waves in a 4x2 grid (wave tile 32x32 as
// 2x2 fragments), BK=32, TRIPLE-buffered LDS, counted-vmcnt raw barriers.
// ---------------------------------------------------------------------------
__global__ __launch_bounds__(512, 4)
void eidetic_mfma(const unsigned short* __restrict__ Xhi, const unsigned short* __restrict__ Xmid,
                  const unsigned short* __restrict__ Whi, const unsigned short* __restrict__ Wmid,
                  const float* __restrict__ X, const float* __restrict__ W,
                  const float* __restrict__ bias, const float* __restrict__ Q,
                  float* __restrict__ out, float* __restrict__ idxo)
{
    __shared__ unsigned char smem[3 * STEP_BYTES];   // 72 KB; buf0 reused for Qs/queue
    const int tid = threadIdx.x;
    const int lane = tid & 63;
    const int w = tid >> 6;                 // 0..7
    const int wm = w >> 1, wn = w & 1;      // 4x2 wave grid over the 128x64 tile
    const int l15 = lane & 15, lg = lane >> 4;

    // XCD-aware swizzle (8192 % 8 == 0 -> bijective); nb fastest within an XCD
    const int bid = blockIdx.x;
    const int swz = ((bid & 7) << 10) | (bid >> 3);
    const int mb = swz >> 6, nb = swz & 63;
    const int m0 = mb << 7, n0 = nb << 6;

    // staging: 24 x 1KB chunks per k-step, 3 per wave (ci = w*3 + i).
    // step image: A.hi [0,8K) A.mid [8K,16K) B.hi [16K,20K) B.mid [20K,24K)
    const unsigned short* csrc[3];
    unsigned cdst[3];
#pragma unroll
    for (int i = 0; i < 3; ++i) {
        const int ci = w * 3 + i;
        const unsigned short* s;
        unsigned d;
        if (ci < 8) {
            s = Xhi + (size_t)mb * 32768 + ci * 512;            d = ci * 1024u;
        } else if (ci < 16) {
            s = Xmid + (size_t)mb * 32768 + (ci - 8) * 512;     d = 8192u + (ci - 8) * 1024u;
        } else if (ci < 20) {
            s = Whi + (size_t)(nb >> 1) * 32768 + (ci - 16) * 1024 + (nb & 1) * 512;
            d = 16384u + (ci - 16) * 1024u;
        } else {
            s = Wmid + (size_t)(nb >> 1) * 32768 + (ci - 20) * 1024 + (nb & 1) * 512;
            d = 20480u + (ci - 20) * 1024u;
        }
        csrc[i] = s + (size_t)lane * 8;
        cdst[i] = d + (unsigned)lane * 16u;
    }

#define STAGE(KS, BUF)                                                          \
    {                                                                           \
        _Pragma("unroll")                                                       \
        for (int i = 0; i < 3; ++i)                                             \
            __builtin_amdgcn_global_load_lds((gu32*)(csrc[i] + (KS) * 4096),    \
                (lu32*)(smem + (BUF) * STEP_BYTES + cdst[i]), 16, 0, 0);        \
    }

    // fragment addresses: [kb(=lg)][row][8 el] -> contiguous 16B per lane
    const unsigned abase = (unsigned)(lg * 2048 + (wm * 32 + l15) * 16);
    const unsigned bbase = 16384u + (unsigned)(lg * 1024 + (wn * 32 + l15) * 16);

    f32x4 acc[2][2];
#pragma unroll
    for (int i = 0; i < 2; ++i)
#pragma unroll
        for (int j = 0; j < 2; ++j) acc[i][j] = (f32x4){0.f, 0.f, 0.f, 0.f};

    STAGE(0, 0)
    STAGE(1, 1)

#pragma unroll
    for (int ks = 0; ks < 8; ++ks) {
        // counted wait: keep the newest stage batch (3 loads) in flight.
        if (ks < 7) asm volatile("s_waitcnt vmcnt(3)" ::: "memory");
        else        asm volatile("s_waitcnt vmcnt(0)" ::: "memory");
        __builtin_amdgcn_s_barrier();
        if (ks < 6) STAGE(ks + 2, (ks + 2) % 3)

        const unsigned buf = (unsigned)(ks % 3) * STEP_BYTES;
        bf16x8 ah[2], am[2], bh[2], bm[2];
#pragma unroll
        for (int f = 0; f < 2; ++f) {
            ah[f] = *(const bf16x8*)(smem + buf + abase + f * 256);
            am[f] = *(const bf16x8*)(smem + buf + 8192u + abase + f * 256);
            bh[f] = *(const bf16x8*)(smem + buf + bbase + f * 256);
            bm[f] = *(const bf16x8*)(smem + buf + 4096u + bbase + f * 256);
        }
#pragma unroll
        for (int fi = 0; fi < 2; ++fi)
#pragma unroll
            for (int fj = 0; fj < 2; ++fj) {
                acc[fi][fj] = __builtin_amdgcn_mfma_f32_16x16x32_bf16(ah[fi], bh[fj], acc[fi][fj], 0, 0, 0);
                acc[fi][fj] = __builtin_amdgcn_mfma_f32_16x16x32_bf16(ah[fi], bm[fj], acc[fi][fj], 0, 0, 0);
                acc[fi][fj] = __builtin_amdgcn_mfma_f32_16x16x32_bf16(am[fi], bh[fj], acc[fi][fj], 0, 0, 0);
            }
    }

    // ---- epilogue: Qs + queue live in buf0 (last compute read buf1, disjoint;
    // the ks=7 barrier guarantees all buf0 readers are done) ----
    float* Qs = (float*)smem;                       // 64*31*4 = 7936 B
    {
        const float* qsrc = Q + (size_t)n0 * NQ;
        for (int t = tid; t < 64 * NQ; t += 512) Qs[t] = qsrc[t];
    }
    int* qcnt = (int*)(smem + 7936);
    int* qbuf = qcnt + 1;                           // ends at 16136 < 24576
    if (tid == 0) *qcnt = 0;
    __syncthreads();

    const int rb = wm * 32 + (lg << 2);             // local row base: + fi*16 + r

    float bv2[2]; int qb2[2]; int ln2[2];
#pragma unroll
    for (int fj = 0; fj < 2; ++fj) {
        const int ln = wn * 32 + fj * 16 + l15;
        ln2[fj] = ln;
        bv2[fj] = bias[n0 + ln];
        qb2[fj] = ln * NQ;
    }

    // fi,r outer / fj inner: the two fj stores cover 128B contiguous per row
    // (with l15 lanes) -> full-line dirty, no partial-line RMW.
#pragma unroll
    for (int fi = 0; fi < 2; ++fi) {
#pragma unroll
        for (int r = 0; r < 4; ++r) {
            const int lrow = rb + fi * 16 + r;
            const size_t rowo = (size_t)(m0 + lrow) * N_DIM + n0;
            float ov[2], cv[2];
#pragma unroll
            for (int fj = 0; fj < 2; ++fj) {
                const float v = acc[fi][fj][r];
                const int qb = qb2[fj];
                // branchless lower-bound (count of q < v) on 31 sorted floats
                int c = (Qs[qb + 15] < v) ? 16 : 0;
                c += (Qs[qb + c + 7] < v) ? 8 : 0;
                c += (Qs[qb + c + 3] < v) ? 4 : 0;
                c += (Qs[qb + c + 1] < v) ? 2 : 0;
                c += (Qs[qb + c] < v) ? 1 : 0;
                // boundary guard: nearest bounds are q[c-1] (< v) and q[c] (>= v)
                bool fl = false;
                if (c > 0)  fl = (v - Qs[qb + c - 1]) < DELTA;
                if (c < NQ) fl |= (Qs[qb + c] - v) < DELTA;
                if (fl) {
                    int slot = atomicAdd(qcnt, 1);
                    if (slot < QCAP) qbuf[slot] = (lrow << 6) | ln2[fj];
                }
                ov[fj] = v + bv2[fj];
                cv[fj] = (float)c;
            }
#pragma unroll
            for (int fj = 0; fj < 2; ++fj) out[rowo + ln2[fj]]  = ov[fj];
#pragma unroll
            for (int fj = 0; fj < 2; ++fj) idxo[rowo + ln2[fj]] = cv[fj];
        }
    }

    // ---- exact recompute for boundary-ambiguous values (~5/block expected) ----
    __syncthreads();
    int tot = *qcnt;
    if (tot > QCAP) tot = QCAP;
    for (int e = tid; e < tot; e += 512) {
        const int pk = qbuf[e];
        const int lm = pk >> 6, lc = pk & 63;
        const float* xr = X + (size_t)(m0 + lm) * K_DIM;
        const float* wr = W + (size_t)(n0 + lc) * K_DIM;
        float a = 0.f;
        // sequential fmaf chain, k ascending: bitwise-matches the reference wx
        for (int k = 0; k < K_DIM; ++k) a = fmaf(xr[k], wr[k], a);
        int c = 0;
        const int qbs = lc * NQ;
        for (int t = 0; t < NQ; ++t) c += (Qs[qbs + t] < a) ? 1 : 0;
        const size_t o = (size_t)(m0 + lm) * N_DIM + (n0 + lc);
        out[o] = a + bias[n0 + lc];
        idxo[o] = (float)c;
    }
#undef STAGE
}

extern "C" void kernel_launch(void* const* d_in, const int* in_sizes, int n_in,
                              void* d_out, int out_size, void* d_ws, size_t ws_size,
                              hipStream_t stream) {
    const float* x    = (const float*)d_in[0];
    const float* wgt  = (const float*)d_in[1];
    const float* bias = (const float*)d_in[2];
    const float* q    = (const float*)d_in[3];
    float* out  = (float*)d_out;
    float* idxo = out + (size_t)B_DIM * N_DIM;

    // workspace: hi/mid bf16 planes, 20.97 MB total (assumes ws_size >= 21MB)
    unsigned short* Xhi  = (unsigned short*)d_ws;
    unsigned short* Xmid = Xhi  + (size_t)B_DIM * K_DIM;
    unsigned short* Whi  = Xmid + (size_t)B_DIM * K_DIM;
    unsigned short* Wmid = Whi  + (size_t)N_DIM * K_DIM;

    hipLaunchKernelGGL(split_pack, dim3(1280), dim3(256), 0, stream,
                       x, wgt, Xhi, Xmid, Whi, Wmid);
    hipLaunchKernelGGL(eidetic_mfma, dim3(8192), dim3(512), 0, stream,
                       Xhi, Xmid, Whi, Wmid, x, wgt, bias, q, out, idxo);
}